// Round 3
// baseline (1033.900 us; speedup 1.0000x reference)
//
#include <hip/hip_runtime.h>
#include <hip/hip_bf16.h>
#include <cstdint>
#include <cstddef>

// Problem constants (B=1)
#define SEQ  2048
#define HID_ 6144
#define NKV  6400   // QKV_OUT
#define NH_  48
#define HD_  128

typedef unsigned short u16;
typedef __bf16 bf16x8 __attribute__((ext_vector_type(8)));
typedef float  f32x4  __attribute__((ext_vector_type(4)));
typedef unsigned short us8 __attribute__((ext_vector_type(8)));

__device__ __forceinline__ void async_ld16(const void* g, void* l) {
  __builtin_amdgcn_global_load_lds(
      (const __attribute__((address_space(1))) unsigned int*)g,
      (__attribute__((address_space(3))) unsigned int*)l, 16, 0, 0);
}

__device__ __forceinline__ u16 f2b(float f) {
  __hip_bfloat16 h = __float2bfloat16(f);
  return *reinterpret_cast<u16*>(&h);
}

// ---------------------------------------------------------------------------
// fp32 -> bf16 convert, 8 elements/thread (32B load, 16B store). n % 8 == 0.
// ---------------------------------------------------------------------------
__global__ void cvt_f32_bf16(const float* __restrict__ in, u16* __restrict__ out,
                             long n8) {
  const long i = (long)blockIdx.x * blockDim.x + threadIdx.x;
  if (i >= n8) return;
  const long o = i * 8;
  const float4 f0 = *(const float4*)(in + o);
  const float4 f1 = *(const float4*)(in + o + 4);
  us8 v;
  v[0] = f2b(f0.x); v[1] = f2b(f0.y); v[2] = f2b(f0.z); v[3] = f2b(f0.w);
  v[4] = f2b(f1.x); v[5] = f2b(f1.y); v[6] = f2b(f1.z); v[7] = f2b(f1.w);
  *(us8*)(out + o) = v;
}

// ---------------------------------------------------------------------------
// GEMM: C[M,N] = A[M,K] @ B[N,K]^T + bias[N]. A,B bf16, fp32 accum,
// fp32 bias, output type OT (u16 bf16 or float).
// m97 structure: 128x128 tile, BK=32, global_load_lds width=16,
// 4 waves in 2x2, each wave 4x4 tiles of 16x16x32 MFMA.
// ---------------------------------------------------------------------------
template <int N, int K, typename OT>
__global__ __launch_bounds__(256, 2)
void gemm_bt_bias(const u16* __restrict__ A, const u16* __restrict__ B,
                  const float* __restrict__ bias, OT* __restrict__ C) {
  __shared__ u16 As[128 * 32];
  __shared__ u16 Bs[128 * 32];
  const int tid  = threadIdx.x;
  const int lane = tid & 63, wave = tid >> 6;
  const int l15  = lane & 15, quad = lane >> 4;
  const int wm = wave >> 1, wn = wave & 1;
  const int m0 = blockIdx.y * 128, n0 = blockIdx.x * 128;

  f32x4 acc[4][4];
#pragma unroll
  for (int i = 0; i < 4; ++i)
#pragma unroll
    for (int j = 0; j < 4; ++j) acc[i][j] = f32x4{0.f, 0.f, 0.f, 0.f};

  // staging: chunk = tid ; row = tid>>2 ; col8 = (tid&3)*8
  const int rowA0 = tid >> 2, col8 = (tid & 3) * 8;
  const u16* gA = A + (size_t)(m0 + rowA0) * K + col8;
  const u16* gB = B + (size_t)(n0 + rowA0) * K + col8;
  u16* lA = As + tid * 8;  // 16B per chunk, lane-contiguous within wave
  u16* lB = Bs + tid * 8;

  for (int k0 = 0; k0 < K; k0 += 32) {
    async_ld16(gA + k0, lA);
    async_ld16(gA + (size_t)64 * K + k0, lA + 256 * 8);
    async_ld16(gB + k0, lB);
    async_ld16(gB + (size_t)64 * K + k0, lB + 256 * 8);
    __syncthreads();  // drains vmcnt(0): staged tiles visible

    const u16* aBase = As + (wm * 64 + l15) * 32 + quad * 8;
    const u16* bBase = Bs + (wn * 64 + l15) * 32 + quad * 8;
    bf16x8 af[4], bfr[4];
#pragma unroll
    for (int i = 0; i < 4; ++i) {
      af[i]  = *(const bf16x8*)(aBase + i * 16 * 32);
      bfr[i] = *(const bf16x8*)(bBase + i * 16 * 32);
    }
#pragma unroll
    for (int i = 0; i < 4; ++i)
#pragma unroll
      for (int j = 0; j < 4; ++j)
        acc[i][j] = __builtin_amdgcn_mfma_f32_16x16x32_bf16(af[i], bfr[j], acc[i][j], 0, 0, 0);
    __syncthreads();  // protect LDS before next stage
  }

  // epilogue: C/D layout col=lane&15, row=(lane>>4)*4+reg  [m89/m91]
#pragma unroll
  for (int j = 0; j < 4; ++j) {
    const int n = n0 + wn * 64 + j * 16 + l15;
    const float bv = bias[n];
#pragma unroll
    for (int i = 0; i < 4; ++i) {
      const int mrow = m0 + wm * 64 + i * 16 + quad * 4;
#pragma unroll
      for (int r = 0; r < 4; ++r) {
        const float v = acc[i][j][r] + bv;
        if constexpr (sizeof(OT) == 2)
          C[(size_t)(mrow + r) * N + n] = (OT)f2b(v);
        else
          C[(size_t)(mrow + r) * N + n] = (OT)v;
      }
    }
  }
}

// ---------------------------------------------------------------------------
// Multi-query causal flash attention (bf16 in/out, fp32 softmax state).
// Block = (head h, 64 q-rows). 4 waves, wave w owns q-strip [q0+16w, +16).
// K staged via global_load_lds in kc-slab layout Ks[kc][64][32]; V staged
// transposed Vt[d][kv] (pad 72) with packed b32 writes; P round-trips LDS
// (C-layout -> A-layout, m120-verified transform).
// ---------------------------------------------------------------------------
__global__ __launch_bounds__(256, 2)
void mqa_flash(const u16* __restrict__ qkv, u16* __restrict__ attn) {
  __shared__ u16 Ks[4 * 64 * 32];  // 16 KB
  __shared__ u16 Vt[128 * 72];     // 18 KB, [d][kv] pad 64->72
  __shared__ u16 Ps[4 * 16 * 72];  // 9 KB, per-wave P[q][kv] pad 64->72
  const int tid  = threadIdx.x;
  const int lane = tid & 63, wave = tid >> 6;
  const int l15  = lane & 15, quad = lane >> 4;
  const int h = blockIdx.y, qb = blockIdx.x;
  const int q0 = qb * 64;
  const float scale = 0.088388347648318447f;  // 1/sqrt(128)

  // Q fragments in registers: A-operand A[m=lane&15][k=quad*8+j]
  bf16x8 qf[4];
  {
    const u16* qp = qkv + (size_t)(q0 + wave * 16 + l15) * NKV + h * HD_ + quad * 8;
#pragma unroll
    for (int kc = 0; kc < 4; ++kc) qf[kc] = *(const bf16x8*)(qp + kc * 32);
  }

  f32x4 oacc[8];
#pragma unroll
  for (int nd = 0; nd < 8; ++nd) oacc[nd] = f32x4{0.f, 0.f, 0.f, 0.f};
  float mrun[4], lrun[4];
#pragma unroll
  for (int r = 0; r < 4; ++r) { mrun[r] = -1e30f; lrun[r] = 0.f; }

  // V staging mapping: 32 kv-pairs x 8 d-groups
  const int kv2 = lane & 31;               // kv pair 0..31
  const int dg  = wave * 2 + (lane >> 5);  // d group 0..7 (16 d each)

  for (int t = 0; t <= qb; ++t) {
    const int kv0 = t * 64;
    // --- K stage: 1024 chunks of 16B into kc-slabs ---
#pragma unroll
    for (int r = 0; r < 4; ++r) {
      const int c = r * 256 + tid;
      const int kc = c >> 8, rr = (c >> 2) & 63, c8 = (c & 3) * 8;
      const u16* gp = qkv + (size_t)(kv0 + rr) * NKV + HID_ + kc * 32 + c8;
      async_ld16(gp, (void*)(Ks + c * 8));
    }
    // --- V stage transposed, packed kv-pairs ---
    {
      const u16* gp0 = qkv + (size_t)(kv0 + kv2 * 2) * NKV + HID_ + HD_ + dg * 16;
      const u16* gp1 = gp0 + NKV;
      us8 a0 = *(const us8*)gp0;
      us8 a1 = *(const us8*)(gp0 + 8);
      us8 b0 = *(const us8*)gp1;
      us8 b1 = *(const us8*)(gp1 + 8);
#pragma unroll
      for (int i = 0; i < 8; ++i) {
        unsigned v0 = (unsigned)a0[i] | ((unsigned)b0[i] << 16);
        unsigned v1 = (unsigned)a1[i] | ((unsigned)b1[i] << 16);
        *(unsigned*)(Vt + (dg * 16 + i) * 72 + kv2 * 2) = v0;
        *(unsigned*)(Vt + (dg * 16 + 8 + i) * 72 + kv2 * 2) = v1;
      }
    }
    __syncthreads();

    // --- S = Q K^T  (16q x 64kv per wave) ---
    f32x4 s[4];
#pragma unroll
    for (int nt = 0; nt < 4; ++nt) {
      f32x4 c4 = f32x4{0.f, 0.f, 0.f, 0.f};
#pragma unroll
      for (int kc = 0; kc < 4; ++kc) {
        bf16x8 kf = *(const bf16x8*)(Ks + kc * 2048 + (nt * 16 + l15) * 32 + quad * 8);
        c4 = __builtin_amdgcn_mfma_f32_16x16x32_bf16(qf[kc], kf, c4, 0, 0, 0);
      }
      s[nt] = c4;
    }

    // --- mask + scale + row max (row = quad*4+r, cols on l15 lanes) ---
    float mt[4] = {-1e30f, -1e30f, -1e30f, -1e30f};
#pragma unroll
    for (int nt = 0; nt < 4; ++nt) {
      const int kvg = kv0 + nt * 16 + l15;
#pragma unroll
      for (int r = 0; r < 4; ++r) {
        const int qg = q0 + wave * 16 + quad * 4 + r;
        float v = s[nt][r] * scale;
        v = (kvg <= qg) ? v : -1e30f;
        s[nt][r] = v;
        mt[r] = fmaxf(mt[r], v);
      }
    }
#pragma unroll
    for (int off = 1; off < 16; off <<= 1)
#pragma unroll
      for (int r = 0; r < 4; ++r) mt[r] = fmaxf(mt[r], __shfl_xor(mt[r], off));

    float alpha[4], rsum[4];
#pragma unroll
    for (int r = 0; r < 4; ++r) {
      const float mnew = fmaxf(mrun[r], mt[r]);
      alpha[r] = __expf(mrun[r] - mnew);
      mrun[r] = mnew;
      rsum[r] = 0.f;
    }
    // --- P = exp(s - m), write to LDS in [q][kv] layout ---
    u16* pw = Ps + wave * (16 * 72);
#pragma unroll
    for (int nt = 0; nt < 4; ++nt)
#pragma unroll
      for (int r = 0; r < 4; ++r) {
        const float p = __expf(s[nt][r] - mrun[r]);
        rsum[r] += p;
        pw[(quad * 4 + r) * 72 + nt * 16 + l15] = f2b(p);
      }
#pragma unroll
    for (int off = 1; off < 16; off <<= 1)
#pragma unroll
      for (int r = 0; r < 4; ++r) rsum[r] += __shfl_xor(rsum[r], off);
#pragma unroll
    for (int r = 0; r < 4; ++r) lrun[r] = lrun[r] * alpha[r] + rsum[r];
#pragma unroll
    for (int nd = 0; nd < 8; ++nd)
#pragma unroll
      for (int r = 0; r < 4; ++r) oacc[nd][r] *= alpha[r];

    // --- O += P @ V ---
#pragma unroll
    for (int kc2 = 0; kc2 < 2; ++kc2) {
      bf16x8 pf = *(const bf16x8*)(pw + l15 * 72 + kc2 * 32 + quad * 8);
#pragma unroll
      for (int nd = 0; nd < 8; ++nd) {
        bf16x8 vf = *(const bf16x8*)(Vt + (nd * 16 + l15) * 72 + kc2 * 32 + quad * 8);
        oacc[nd] = __builtin_amdgcn_mfma_f32_16x16x32_bf16(pf, vf, oacc[nd], 0, 0, 0);
      }
    }
    __syncthreads();
  }

  // --- epilogue: O / l -> attn[S, HID] (bf16) ---
#pragma unroll
  for (int r = 0; r < 4; ++r) {
    const int qg = q0 + wave * 16 + quad * 4 + r;
    const float inv = 1.f / lrun[r];
#pragma unroll
    for (int nd = 0; nd < 8; ++nd)
      attn[(size_t)qg * HID_ + h * HD_ + nd * 16 + l15] = f2b(oacc[nd][r] * inv);
  }
}

// ---------------------------------------------------------------------------
extern "C" void kernel_launch(void* const* d_in, const int* in_sizes, int n_in,
                              void* d_out, int out_size, void* d_ws, size_t ws_size,
                              hipStream_t stream) {
  const float* x    = (const float*)d_in[0];  // [2048, 6144] fp32
  const float* wqkv = (const float*)d_in[1];  // [6400, 6144] fp32
  const float* bqkv = (const float*)d_in[2];  // [6400] fp32
  const float* wo   = (const float*)d_in[3];  // [6144, 6144] fp32
  const float* bo   = (const float*)d_in[4];  // [6144] fp32
  float* out = (float*)d_out;                 // [2048, 6144] fp32

  // workspace layout (all 16B-aligned)
  u16* xb     = (u16*)d_ws;                             // 25.2 MB
  u16* wqkvb  = xb + (size_t)SEQ * HID_;                // 78.6 MB
  u16* wob    = wqkvb + (size_t)NKV * HID_;             // 75.5 MB
  u16* qkvws  = wob + (size_t)HID_ * HID_;              // 26.2 MB
  u16* attnws = qkvws + (size_t)SEQ * NKV;              // 25.2 MB
  // total ~230.7 MB

  // 0) fp32 -> bf16 converts
  {
    const long n8x = (long)SEQ * HID_ / 8;
    cvt_f32_bf16<<<(n8x + 255) / 256, 256, 0, stream>>>(x, xb, n8x);
    const long n8q = (long)NKV * HID_ / 8;
    cvt_f32_bf16<<<(n8q + 255) / 256, 256, 0, stream>>>(wqkv, wqkvb, n8q);
    const long n8o = (long)HID_ * HID_ / 8;
    cvt_f32_bf16<<<(n8o + 255) / 256, 256, 0, stream>>>(wo, wob, n8o);
  }

  // 1) fused QKV projection (bf16 out)
  gemm_bt_bias<NKV, HID_, u16><<<dim3(NKV / 128, SEQ / 128), 256, 0, stream>>>(
      xb, wqkvb, bqkv, qkvws);
  // 2) multi-query causal flash attention
  mqa_flash<<<dim3(SEQ / 64, NH_), 256, 0, stream>>>(qkvws, attnws);
  // 3) output projection (fp32 out)
  gemm_bt_bias<HID_, HID_, float><<<dim3(HID_ / 128, SEQ / 128), 256, 0, stream>>>(
      attnws, wob, bo, out);
}